// Round 1
// baseline (83.693 us; speedup 1.0000x reference)
//
#include <hip/hip_runtime.h>

#define DIM 4096
#define NQ 12
#define DEPTH 4
#define NTHREADS 1024

// Reference: U = G_last ... G_first (gates LEFT-multiplied onto U), then
// out = U @ e0. So out = sequential state-vector sim starting from e0.
// Qubit q lives at bit position (11 - q) of the flat index (row-major
// reshape puts qubit 0 at the MSB).
__global__ __launch_bounds__(NTHREADS) void qc12_kernel(
    const float* __restrict__ x,      // [12]
    const float* __restrict__ theta,  // [4,12]
    const float* __restrict__ w_out,  // [2,4096]
    const float* __restrict__ b_out,  // [2]
    float* __restrict__ out)          // [2 + 4096]
{
    __shared__ float bufA[DIM];
    __shared__ float bufB[DIM];
    __shared__ float red[32];   // 16 waves x 2 classes

    const int tid = threadIdx.x;

    float* cur = bufA;
    float* alt = bufB;

    // state = e0
    #pragma unroll
    for (int k = 0; k < DIM / NTHREADS; ++k) cur[tid + k * NTHREADS] = 0.0f;
    if (tid == 0) cur[0] = 1.0f;
    __syncthreads();

    for (int d = 0; d < DEPTH; ++d) {
        // ---- RY(theta[d][q] + 0.1*x[q]) on each qubit q ----
        for (int q = 0; q < NQ; ++q) {
            const float a = 0.5f * (theta[d * NQ + q] + 0.1f * x[q]);
            float s, c;
            sincosf(a, &s, &c);
            const int b   = 11 - q;      // bit position of qubit q
            const int bit = 1 << b;
            #pragma unroll
            for (int k = 0; k < (DIM / 2) / NTHREADS; ++k) {
                const int p  = tid + k * NTHREADS;         // pair index
                const int i0 = ((p >> b) << (b + 1)) | (p & (bit - 1));
                const int i1 = i0 | bit;
                const float v0 = cur[i0];
                const float v1 = cur[i1];
                // RY = [[c, -s], [s, c]] applied to (v0, v1)
                cur[i0] = c * v0 - s * v1;
                cur[i1] = s * v0 + c * v1;
            }
            __syncthreads();
        }

        // ---- CNOT ring: q -> (q+1)%12, composed into ONE gather ----
        // Each CNOT(c,t): new[i] = old[i ^ (tbit * cbit(i))].
        // Composition of gates g0..g11 (applied in that order) reads
        // old[f_g0(f_g1(...f_g11(i)))] -> walk gates in REVERSE.
        #pragma unroll
        for (int k = 0; k < DIM / NTHREADS; ++k) {
            const int i = tid + k * NTHREADS;
            int j = i;
            #pragma unroll
            for (int q = NQ - 1; q >= 0; --q) {
                const int cb = 11 - q;                 // control bit pos
                const int tb = 11 - ((q + 1) % NQ);    // target bit pos
                j ^= ((j >> cb) & 1) << tb;
            }
            alt[i] = cur[j];
        }
        __syncthreads();
        float* t = cur; cur = alt; alt = t;
    }

    // ---- probs = state^2 ; logits = probs @ w_out.T + b_out ----
    float p0 = 0.0f, p1 = 0.0f;
    #pragma unroll
    for (int k = 0; k < DIM / NTHREADS; ++k) {
        const int i = tid + k * NTHREADS;
        const float v  = cur[i];
        const float pr = v * v;
        p0 += pr * w_out[i];
        p1 += pr * w_out[DIM + i];
        out[2 + i] = v;              // second tuple element: the state
    }
    // wave-64 butterfly reduce
    #pragma unroll
    for (int off = 32; off > 0; off >>= 1) {
        p0 += __shfl_down(p0, off, 64);
        p1 += __shfl_down(p1, off, 64);
    }
    const int wave = tid >> 6;
    const int lane = tid & 63;
    if (lane == 0) { red[wave] = p0; red[16 + wave] = p1; }
    __syncthreads();
    if (tid == 0) {
        float s0 = 0.0f, s1 = 0.0f;
        #pragma unroll
        for (int w = 0; w < NTHREADS / 64; ++w) { s0 += red[w]; s1 += red[16 + w]; }
        out[0] = s0 + b_out[0];      // first tuple element: logits
        out[1] = s1 + b_out[1];
    }
}

extern "C" void kernel_launch(void* const* d_in, const int* in_sizes, int n_in,
                              void* d_out, int out_size, void* d_ws, size_t ws_size,
                              hipStream_t stream) {
    const float* x     = (const float*)d_in[0];  // [12]
    const float* theta = (const float*)d_in[1];  // [4,12]
    const float* w_out = (const float*)d_in[2];  // [2,4096]
    const float* b_out = (const float*)d_in[3];  // [2]
    float* out = (float*)d_out;                  // [2 + 4096]

    qc12_kernel<<<1, NTHREADS, 0, stream>>>(x, theta, w_out, b_out, out);
}

// Round 2
// 67.004 us; speedup vs baseline: 1.2491x; 1.2491x over previous
//
#include <hip/hip_runtime.h>

#define DIM 4096
#define NQ 12
#define NT 1024

// CNOT-ring permutation: new[i] = old[P(i)], P = composition of the 12
// CNOTs walked in reverse (verified exact in round 1, absmax 0.0).
// Each CNOT is GF(2)-linear, so P is linear: P(a^b) = P(a)^P(b), P(0)=0.
__host__ __device__ constexpr int permP_c(int i) {
    int j = i;
    for (int q = NQ - 1; q >= 0; --q) {
        const int cb = 11 - q;                 // control bit pos
        const int tb = 11 - ((q + 1) % NQ);    // target bit pos
        j ^= ((j >> cb) & 1) << tb;
    }
    return j;
}

__global__ __launch_bounds__(NT) void qc12_kernel(
    const float* __restrict__ x,      // [12]
    const float* __restrict__ theta,  // [4,12]
    const float* __restrict__ w_out,  // [2,4096]
    const float* __restrict__ b_out,  // [2]
    float* __restrict__ out)          // [2 + 4096]
{
    __shared__ float A[DIM];
    __shared__ float B[DIM];
    __shared__ float cT[4 * NQ];
    __shared__ float sT[4 * NQ];
    __shared__ float red[32];

    const int t = threadIdx.x;

    // ---- phase 0: all 48 half-angle sincos, once ----
    if (t < 4 * NQ) {
        const int q = t % NQ;
        const float a = 0.5f * (theta[t] + 0.1f * x[q]);
        sincosf(a, &sT[t], &cT[t]);
    }
    __syncthreads();

    // ---- layer 1 on e0: product state, CNOT perm folded into write ----
    // state[j] = prod_q (bit at pos 11-q of j ? s_q : c_q); A[i] = state[P(i)]
    {
        const int i0 = 4 * t;
        const int jb = permP_c(i0);
        #pragma unroll
        for (int k = 0; k < 4; ++k) {
            int j = jb;
            if (k & 1) j ^= permP_c(1);
            if (k & 2) j ^= permP_c(2);
            float v = 1.0f;
            #pragma unroll
            for (int b = 0; b < NQ; ++b) {
                const int q = 11 - b;
                v *= ((j >> b) & 1) ? sT[q] : cT[q];
            }
            A[i0 + k] = v;
        }
    }
    __syncthreads();

    // ---- fused 2-qubit (4x4) sweep ----
    // Sweep s covers qubits (2s, 2s+1) -> bit positions b1=11-2s, b0=b1-1.
    // RY gates on distinct qubits commute, so sweep order is free.
    // fused=true: read rbuf at P(idx) (folds previous layer's CNOT ring).
    auto sweep = [&](int d, int s, float* rbuf, float* wbuf, bool fused) {
        const int q0 = 2 * s, q1 = 2 * s + 1;
        const float c1 = cT[d * NQ + q0], s1 = sT[d * NQ + q0]; // bit b1
        const float c0 = cT[d * NQ + q1], s0 = sT[d * NQ + q1]; // bit b0
        const int b0 = 10 - 2 * s;
        const int m0 = 1 << b0;
        const int base = ((t >> b0) << (b0 + 2)) | (t & (m0 - 1));
        const int i0 = base, i1 = base | m0, i2 = base | (m0 << 1),
                  i3 = base | (3 * m0);
        int j0 = i0, j1 = i1, j2 = i2, j3 = i3;
        if (fused) {
            j0 = permP_c(i0);           // runtime (base); linear for the rest
            j1 = j0 ^ permP_c(m0);      // compile-time constants
            j2 = j0 ^ permP_c(m0 << 1);
            j3 = j1 ^ permP_c(m0 << 1);
        }
        const float v0 = rbuf[j0], v1 = rbuf[j1], v2 = rbuf[j2], v3 = rbuf[j3];
        // gate on b0 (qubit q1): pairs (v0,v1),(v2,v3)
        const float t0 = c0 * v0 - s0 * v1, t1 = s0 * v0 + c0 * v1;
        const float t2 = c0 * v2 - s0 * v3, t3 = s0 * v2 + c0 * v3;
        // gate on b1 (qubit q0): pairs (t0,t2),(t1,t3)
        wbuf[i0] = c1 * t0 - s1 * t2;
        wbuf[i2] = s1 * t0 + c1 * t2;
        wbuf[i1] = c1 * t1 - s1 * t3;
        wbuf[i3] = s1 * t1 + c1 * t3;
    };

    // s=5 sweep (b0=0): contiguous quad -> float4 LDS access (avoids the
    // 8-way bank conflict of 4 scalar stride-4 reads).
    auto sweep5_vec = [&](int d, float* buf) {
        const float c1 = cT[d * NQ + 10], s1 = sT[d * NQ + 10];
        const float c0 = cT[d * NQ + 11], s0 = sT[d * NQ + 11];
        float4 v = ((float4*)buf)[t];
        const float t0 = c0 * v.x - s0 * v.y, t1 = s0 * v.x + c0 * v.y;
        const float t2 = c0 * v.z - s0 * v.w, t3 = s0 * v.z + c0 * v.w;
        v.x = c1 * t0 - s1 * t2;
        v.z = s1 * t0 + c1 * t2;
        v.y = c1 * t1 - s1 * t3;
        v.w = s1 * t1 + c1 * t3;
        ((float4*)buf)[t] = v;
    };

    // ---- layer 2 (d=1): in place on A (layer-1 perm already applied) ----
    #pragma unroll
    for (int s = 0; s < 5; ++s) { sweep(1, s, A, A, false); __syncthreads(); }
    sweep5_vec(1, A); __syncthreads();

    // ---- layer 3 (d=2): first sweep folds layer-2 CNOT ring, A -> B ----
    sweep(2, 0, A, B, true); __syncthreads();
    #pragma unroll
    for (int s = 1; s < 5; ++s) { sweep(2, s, B, B, false); __syncthreads(); }
    sweep5_vec(2, B); __syncthreads();

    // ---- layer 4 (d=3): first sweep folds layer-3 CNOT ring, B -> A ----
    sweep(3, 0, B, A, true); __syncthreads();
    #pragma unroll
    for (int s = 1; s < 5; ++s) { sweep(3, s, A, A, false); __syncthreads(); }
    sweep5_vec(3, A); __syncthreads();

    // ---- epilogue: layer-4 CNOT folded into read; probs, logits, state ----
    float p0 = 0.0f, p1 = 0.0f;
    {
        const int i0 = 4 * t;
        const int jb = permP_c(i0);
        const float4 w0 = ((const float4*)w_out)[t];
        const float4 w1 = ((const float4*)(w_out + DIM))[t];
        const float wa0[4] = {w0.x, w0.y, w0.z, w0.w};
        const float wa1[4] = {w1.x, w1.y, w1.z, w1.w};
        #pragma unroll
        for (int k = 0; k < 4; ++k) {
            int j = jb;
            if (k & 1) j ^= permP_c(1);
            if (k & 2) j ^= permP_c(2);
            const float v = A[j];
            out[2 + i0 + k] = v;
            const float pr = v * v;
            p0 += pr * wa0[k];
            p1 += pr * wa1[k];
        }
    }
    #pragma unroll
    for (int off = 32; off > 0; off >>= 1) {
        p0 += __shfl_down(p0, off, 64);
        p1 += __shfl_down(p1, off, 64);
    }
    const int wave = t >> 6;
    const int lane = t & 63;
    if (lane == 0) { red[wave] = p0; red[16 + wave] = p1; }
    __syncthreads();
    if (t == 0) {
        float s0 = 0.0f, s1 = 0.0f;
        #pragma unroll
        for (int w = 0; w < NT / 64; ++w) { s0 += red[w]; s1 += red[16 + w]; }
        out[0] = s0 + b_out[0];
        out[1] = s1 + b_out[1];
    }
}

extern "C" void kernel_launch(void* const* d_in, const int* in_sizes, int n_in,
                              void* d_out, int out_size, void* d_ws, size_t ws_size,
                              hipStream_t stream) {
    const float* x     = (const float*)d_in[0];  // [12]
    const float* theta = (const float*)d_in[1];  // [4,12]
    const float* w_out = (const float*)d_in[2];  // [2,4096]
    const float* b_out = (const float*)d_in[3];  // [2]
    float* out = (float*)d_out;                  // [2 + 4096]

    qc12_kernel<<<1, NT, 0, stream>>>(x, theta, w_out, b_out, out);
}

// Round 3
// 64.375 us; speedup vs baseline: 1.3001x; 1.0408x over previous
//
#include <hip/hip_runtime.h>

#define DIM 4096
#define NQ 12
#define NT 256

// CNOT-ring permutation P (new[i] = old[P(i)]), bit-linear, closed form.
// Derived from the reverse-walk composition; verified on HW in rounds 1-2
// (absmax 0.0 / 4.8e-7): bp' = bp^b(p+1) (p=0..9), b10' = b10^b11^b0,
// b11' = b11^b0  =>  P(i) = (i ^ (i>>1)) & 0xFFF, then ^0xC00 if bit0.
__device__ __forceinline__ int permP(int i) {
    return ((i ^ (i >> 1)) & 0xFFF) ^ ((i & 1) ? 0xC00 : 0);
}
// P(m << 8) for m in [0,16): only touches bits [11:7].
__device__ __forceinline__ int pm8(int m) {
    return ((m << 8) ^ (m << 7)) & 0xFFF;
}

// Apply 4 RY gates to the 16 register-resident amps v[m], where local bit j
// of m corresponds to qubit (qbase - j) of layer d.
// RY pair rule (einsum 'ab,xby->xay', g=[[c,-s],[s,c]]):
//   new0 = c*v0 - s*v1 ; new1 = s*v0 + c*v1   (v0 = element with bit clear)
__device__ __forceinline__ void gates4(float v[16], const float* cT,
                                       const float* sT, int d, int qbase) {
    #pragma unroll
    for (int j = 0; j < 4; ++j) {
        const float c = cT[d * NQ + (qbase - j)];
        const float s = sT[d * NQ + (qbase - j)];
        #pragma unroll
        for (int m = 0; m < 16; ++m) {
            if (m & (1 << j)) continue;
            const float v0 = v[m];
            const float v1 = v[m | (1 << j)];
            v[m]            = c * v0 - s * v1;
            v[m | (1 << j)] = s * v0 + c * v1;
        }
    }
}

__global__ __launch_bounds__(NT) void qc12_kernel(
    const float* __restrict__ x,      // [12]
    const float* __restrict__ theta,  // [4,12]
    const float* __restrict__ w_out,  // [2,4096]
    const float* __restrict__ b_out,  // [2]
    float* __restrict__ out)          // [2 + 4096]
{
    __shared__ __align__(16) float A[DIM];
    __shared__ __align__(16) float B[DIM];
    __shared__ float cT[4 * NQ];
    __shared__ float sT[4 * NQ];
    __shared__ float red[8];

    const int t = threadIdx.x;

    // ---- all 48 half-angle sincos, once ----
    if (t < 4 * NQ) {
        const int q = t % NQ;
        const float a = 0.5f * (theta[t] + 0.1f * x[q]);
        sincosf(a, &sT[t], &cT[t]);
    }
    __syncthreads();

    // Sweep A: group = index bits [11:8] (qubits 3..0), others fixed = t.
    // Reads P-folded from src (folds the previous layer's CNOT ring),
    // writes dst at natural positions. Bank pattern: reads 2-way (free),
    // writes conflict-free.
    auto sweepAf = [&](const float* src, float* dst, int d) {
        const int pt = permP(t);
        float v[16];
        #pragma unroll
        for (int m = 0; m < 16; ++m) v[m] = src[pt ^ pm8(m)];
        gates4(v, cT, sT, d, 3);
        #pragma unroll
        for (int m = 0; m < 16; ++m) dst[(m << 8) | t] = v[m];
    };
    // Sweep B: bits [7:4] (qubits 7..4), in place. ~2-way banks (free).
    auto sweepB = [&](float* buf, int d) {
        const int base = ((t >> 4) << 8) | (t & 15);
        float v[16];
        #pragma unroll
        for (int m = 0; m < 16; ++m) v[m] = buf[base | (m << 4)];
        gates4(v, cT, sT, d, 7);
        #pragma unroll
        for (int m = 0; m < 16; ++m) buf[base | (m << 4)] = v[m];
    };
    // Sweep C: bits [3:0] (qubits 11..8), in place, contiguous float4
    // (LDS-bandwidth-optimal).
    auto sweepC = [&](float* buf, int d) {
        float4* b4 = (float4*)buf;
        float v[16];
        #pragma unroll
        for (int r = 0; r < 4; ++r) {
            const float4 q = b4[4 * t + r];
            v[4 * r + 0] = q.x; v[4 * r + 1] = q.y;
            v[4 * r + 2] = q.z; v[4 * r + 3] = q.w;
        }
        gates4(v, cT, sT, d, 11);
        #pragma unroll
        for (int r = 0; r < 4; ++r)
            b4[4 * t + r] = make_float4(v[4 * r], v[4 * r + 1],
                                        v[4 * r + 2], v[4 * r + 3]);
    };

    // ---- fused pass: layer-1 product state (on e0) at P-mapped indices,
    //      plus layer-2's bits[11:8] gates, written straight to A ----
    {
        const int pt = permP(t);
        // common factor over index bits [6:0] (pm8 never touches them)
        float lowp = 1.0f;
        #pragma unroll
        for (int b = 0; b < 7; ++b)
            lowp *= ((pt >> b) & 1) ? sT[11 - b] : cT[11 - b];  // layer d=0
        float v[16];
        #pragma unroll
        for (int m = 0; m < 16; ++m) {
            const int idx = pt ^ pm8(m);
            float p = lowp;
            #pragma unroll
            for (int b = 7; b < 12; ++b)
                p *= ((idx >> b) & 1) ? sT[11 - b] : cT[11 - b];
            v[m] = p;
        }
        gates4(v, cT, sT, 1, 3);  // layer 2, qubits 3..0
        #pragma unroll
        for (int m = 0; m < 16; ++m) A[(m << 8) | t] = v[m];
    }
    __syncthreads();

    // ---- layer 2 rest ----
    sweepB(A, 1); __syncthreads();
    sweepC(A, 1); __syncthreads();
    // ---- layer 3 (sweep A folds layer-2 ring, A -> B) ----
    sweepAf(A, B, 2); __syncthreads();
    sweepB(B, 2); __syncthreads();
    sweepC(B, 2); __syncthreads();
    // ---- layer 4 (sweep A folds layer-3 ring, B -> A) ----
    sweepAf(B, A, 3); __syncthreads();
    sweepB(A, 3); __syncthreads();
    sweepC(A, 3); __syncthreads();

    // ---- epilogue: layer-4 ring folded into reads; state + logits ----
    float p0 = 0.0f, p1 = 0.0f;
    {
        const int pt = permP(t);
        #pragma unroll
        for (int m = 0; m < 16; ++m) {
            const int i = (m << 8) | t;         // coalesced global pattern
            const float val = A[pt ^ pm8(m)];   // 2-way LDS banks (free)
            out[2 + i] = val;
            const float pr = val * val;
            p0 += pr * w_out[i];
            p1 += pr * w_out[DIM + i];
        }
    }
    #pragma unroll
    for (int off = 32; off > 0; off >>= 1) {
        p0 += __shfl_down(p0, off, 64);
        p1 += __shfl_down(p1, off, 64);
    }
    const int wave = t >> 6;
    const int lane = t & 63;
    if (lane == 0) { red[wave] = p0; red[4 + wave] = p1; }
    __syncthreads();
    if (t == 0) {
        out[0] = red[0] + red[1] + red[2] + red[3] + b_out[0];
        out[1] = red[4] + red[5] + red[6] + red[7] + b_out[1];
    }
}

extern "C" void kernel_launch(void* const* d_in, const int* in_sizes, int n_in,
                              void* d_out, int out_size, void* d_ws, size_t ws_size,
                              hipStream_t stream) {
    const float* x     = (const float*)d_in[0];  // [12]
    const float* theta = (const float*)d_in[1];  // [4,12]
    const float* w_out = (const float*)d_in[2];  // [2,4096]
    const float* b_out = (const float*)d_in[3];  // [2]
    float* out = (float*)d_out;                  // [2 + 4096]

    qc12_kernel<<<1, NT, 0, stream>>>(x, theta, w_out, b_out, out);
}